// Round 14
// baseline (456.723 us; speedup 1.0000x reference)
//
#include <hip/hip_runtime.h>

#define Bb 64
#define Ss 512
#define INn 1024
#define Ee 128
#define Hh 8
#define Dd 16
#define NLl 4

typedef unsigned short u16;
typedef __attribute__((ext_vector_type(8))) short short8;
typedef __attribute__((ext_vector_type(4))) float f32x4;

__device__ __forceinline__ float b2f(unsigned u) { return __uint_as_float(u << 16); }
__device__ __forceinline__ u16 f2b(float f) {
    unsigned u = __float_as_uint(f);
    unsigned r = u + 0x7FFFu + ((u >> 16) & 1u);
    return (u16)(r >> 16);
}
__device__ __forceinline__ uint2 pk4(float4 f) {
    uint2 r;
    r.x = (unsigned)f2b(f.x) | ((unsigned)f2b(f.y) << 16);
    r.y = (unsigned)f2b(f.z) | ((unsigned)f2b(f.w) << 16);
    return r;
}

#define GLOAD_LDS16(g, l) __builtin_amdgcn_global_load_lds( \
    (const __attribute__((address_space(1))) void*)(g),     \
    (__attribute__((address_space(3))) void*)(l), 16, 0, 0)

#define MFMA16(a, b, c) __builtin_amdgcn_mfma_f32_16x16x32_bf16((a), (b), (c), 0, 0, 0)

// ---------------- prep: lengths (block 0) + pe (1-32) + weight transpose (33-256) ----
// Weights stored TRANSPOSED (N,K), XOR-swizzled: (n,k) lives at k ^ ((n&7)<<3).
__global__ __launch_bounds__(256) void prep_kernel(const unsigned char* __restrict__ m,
                                                   int* __restrict__ lengths,
                                                   float* __restrict__ pe,
                                                   const float* __restrict__ ew,
                                                   const float* __restrict__ qw,
                                                   const float* __restrict__ ow,
                                                   const float* __restrict__ f1w,
                                                   const float* __restrict__ f2w,
                                                   u16* __restrict__ we, u16* __restrict__ wq,
                                                   u16* __restrict__ wo, u16* __restrict__ wf1,
                                                   u16* __restrict__ wf2) {
    const int bid = blockIdx.x, tid = threadIdx.x;
    if (bid == 0) {
        __shared__ int lf[3];
        __shared__ int part[256];
        if (tid < 3) lf[tid] = 0;
        __syncthreads();
        int l0 = 0, l1 = 0, l23 = 0;
        for (int i = tid * 128; i < tid * 128 + 128; ++i) {  // first 32768 bytes: safe
            if (m[i]) { int md = i & 3; if (md == 0) l0 = 1; else if (md == 1) l1 = 1; else l23 = 1; }
        }
        if (l0) atomicOr(&lf[0], 1);
        if (l1) atomicOr(&lf[1], 1);
        if (l23) atomicOr(&lf[2], 1);
        __syncthreads();
        int enc = lf[1] ? 1 : (lf[2] ? 2 : 0);  // 1=uint8, 2=float32, 0=int32
        int b = tid >> 2, q = tid & 3, cnt = 0;
        for (int s = q * 128; s < q * 128 + 128; ++s) {
            int idx = b * Ss + s;
            int mm;
            if (enc == 1)      mm = (m[idx] != 0);
            else if (enc == 2) mm = (((const float*)(const void*)m)[idx] != 0.0f);
            else               mm = (((const int*)(const void*)m)[idx] != 0);
            cnt += (mm == 0);  // monotone mask: zero count == length
        }
        part[tid] = cnt;
        __syncthreads();
        if (tid < 64)
            lengths[tid] = part[tid * 4] + part[tid * 4 + 1] + part[tid * 4 + 2] + part[tid * 4 + 3];
        return;
    }
    if (bid <= 32) {
        for (int i = tid; i < 2048; i += 256) {
            int idx = (bid - 1) * 2048 + i;
            int s = idx >> 7, e = idx & 127;
            float expo = (float)(2 * (e >> 1)) * (1.0f / 128.0f);
            float freq = powf(10000.0f, -expo);
            float angle = (float)s * freq;
            pe[idx] = (e & 1) ? cosf(angle) : sinf(angle);
        }
        return;
    }
    int tb = bid - 33;
    const float* src; u16* dst; int K, N, tile;
    if (tb < 32)       { src = ew;  dst = we;  K = 1024; N = 128; tile = tb; }
    else if (tb < 80)  { int b = tb - 32;  int mat = b >> 2; src = qw  + (size_t)mat * 16384; dst = wq  + (size_t)mat * 16384; K = 128; N = 128; tile = b & 3; }
    else if (tb < 96)  { int b = tb - 80;  int mat = b >> 2; src = ow  + (size_t)mat * 16384; dst = wo  + (size_t)mat * 16384; K = 128; N = 128; tile = b & 3; }
    else if (tb < 160) { int b = tb - 96;  int mat = b >> 4; src = f1w + (size_t)mat * 65536; dst = wf1 + (size_t)mat * 65536; K = 128; N = 512; tile = b & 15; }
    else               { int b = tb - 160; int mat = b >> 4; src = f2w + (size_t)mat * 65536; dst = wf2 + (size_t)mat * 65536; K = 512; N = 128; tile = b & 15; }
    int ktiles = K >> 6;
    int k0 = (tile % ktiles) * 64, n0 = (tile / ktiles) * 64;
    __shared__ __align__(16) u16 t_s[64 * 68];
    int r = tid >> 2, cq = (tid & 3) * 16;
    const float* sp = src + (size_t)(k0 + r) * N + n0 + cq;
#pragma unroll
    for (int i = 0; i < 4; ++i) {
        float4 f = *(const float4*)(sp + 4 * i);
        *(uint2*)&t_s[r * 68 + cq + 4 * i] = pk4(f);
    }
    __syncthreads();
    u16 tmp[16];
#pragma unroll
    for (int kk = 0; kk < 16; ++kk) tmp[kk] = t_s[(cq + kk) * 68 + r];
    int rowg = n0 + r;
    int x = (rowg & 7) << 3;
    u16* base = dst + (size_t)rowg * K;
    *(uint4*)(base + ((k0 + cq) ^ x))     = ((uint4*)tmp)[0];
    *(uint4*)(base + ((k0 + cq + 8) ^ x)) = ((uint4*)tmp)[1];
}

// ------- embed GEMM: h(S,B rows, swizzled) = x(f32) @ wt_embed^T + bias + pe -------
__global__ __launch_bounds__(256) void embed_gemm(const float* __restrict__ X,
                                                  const u16* __restrict__ Wt,
                                                  const float* __restrict__ bias,
                                                  const float* __restrict__ pe,
                                                  u16* __restrict__ C) {
    __shared__ __align__(16) u16 Af[64 * 68];
    __shared__ __align__(16) u16 Bs[2][128 * 64];
    const int tid = threadIdx.x;
    const int w = tid >> 6, lane = tid & 63, l16 = lane & 15, lhi = lane >> 4;
    const int row0 = blockIdx.x * 64;
    const int xr = (l16 & 7) << 3;
    f32x4 acc[8];
#pragma unroll
    for (int ni = 0; ni < 8; ++ni) acc[ni] = (f32x4){0.f, 0.f, 0.f, 0.f};

    const int ar = tid >> 2, ak = (tid & 3) * 16;
    const int crow = tid >> 3, cc8 = (tid & 7) * 8;
    const int wave_lds = w * 512;
    const u16* Bbase = Wt + cc8;
    const float* Arow = X + (size_t)(row0 + ar) * 1024 + ak;

#pragma unroll
    for (int i = 0; i < 4; ++i)
        GLOAD_LDS16(Bbase + (size_t)(i * 32 + crow) * 1024, &Bs[0][i * 2048 + wave_lds]);

    for (int it = 0; it < 16; ++it) {
        const int k0 = it * 64;
        __syncthreads();
#pragma unroll
        for (int i = 0; i < 4; ++i) {
            float4 f = *(const float4*)(Arow + k0 + 4 * i);
            *(uint2*)&Af[ar * 68 + ak + 4 * i] = pk4(f);
        }
        __syncthreads();
        if (it < 15) {
#pragma unroll
            for (int i = 0; i < 4; ++i)
                GLOAD_LDS16(Bbase + (size_t)(i * 32 + crow) * 1024 + k0 + 64,
                            &Bs[(it + 1) & 1][i * 2048 + wave_lds]);
        }
#pragma unroll
        for (int ks = 0; ks < 2; ++ks) {
            short8 af;
            ((uint2*)&af)[0] = *(const uint2*)&Af[(w * 16 + l16) * 68 + ks * 32 + lhi * 8];
            ((uint2*)&af)[1] = *(const uint2*)&Af[(w * 16 + l16) * 68 + ks * 32 + lhi * 8 + 4];
#pragma unroll
            for (int ni = 0; ni < 8; ++ni) {
                short8 bfr = *(const short8*)&Bs[it & 1][(ni * 16 + l16) * 64 + ((ks * 32 + lhi * 8) ^ xr)];
                acc[ni] = MFMA16(af, bfr, acc[ni]);
            }
        }
    }
    float biasr[8];
#pragma unroll
    for (int ni = 0; ni < 8; ++ni) biasr[ni] = bias[ni * 16 + l16];
#pragma unroll
    for (int reg = 0; reg < 4; ++reg) {
        int r = row0 + w * 16 + lhi * 4 + reg;      // b-major row b*512+s
        int s = r & 511;
        int bidx = r >> 9;
        int orow = s * 64 + bidx;                   // (S,B) row
        int xo = (bidx & 7) << 3;
        const float* per = pe + (size_t)s * 128;
        u16* crw = C + (size_t)orow * 128;
#pragma unroll
        for (int ni = 0; ni < 8; ++ni) {
            int c = ni * 16 + l16;
            crw[c ^ xo] = f2b(acc[ni][reg] + biasr[ni] + per[c]);
        }
    }
}

// ------- QKV GEMM (layer 0 only): K=128 single-shot; A and W staged via gload_lds ----
__global__ __launch_bounds__(256) void qkv_gemm(const u16* __restrict__ A,
                                                const u16* __restrict__ Wt,
                                                const float* __restrict__ bias,
                                                u16* __restrict__ Cq,
                                                u16* __restrict__ Ckv) {
    __shared__ __align__(16) u16 As[128 * 128];
    __shared__ __align__(16) u16 Bs[128 * 128];
    const int tid = threadIdx.x, w = tid >> 6, lane = tid & 63;
    const int l16 = lane & 15, lhi = lane >> 4;
    const int row0 = blockIdx.x * 128, col0 = blockIdx.y * 128;
    const int so = w * 512 + lane * 8;
    const int xr = (l16 & 7) << 3;
#pragma unroll
    for (int i = 0; i < 8; ++i) {
        GLOAD_LDS16(A + (size_t)row0 * 128 + i * 2048 + so, &As[i * 2048 + w * 512]);
        GLOAD_LDS16(Wt + (size_t)col0 * 128 + i * 2048 + so, &Bs[i * 2048 + w * 512]);
    }
    __syncthreads();
    f32x4 acc[2][8];
#pragma unroll
    for (int mi = 0; mi < 2; ++mi)
#pragma unroll
        for (int ni = 0; ni < 8; ++ni) acc[mi][ni] = (f32x4){0.f, 0.f, 0.f, 0.f};
#pragma unroll
    for (int ks = 0; ks < 4; ++ks) {
        const int ko = (ks * 32 + lhi * 8) ^ xr;
        short8 af[2], bfr[8];
#pragma unroll
        for (int mi = 0; mi < 2; ++mi)
            af[mi] = *(const short8*)&As[(w * 32 + mi * 16 + l16) * 128 + ko];
#pragma unroll
        for (int ni = 0; ni < 8; ++ni)
            bfr[ni] = *(const short8*)&Bs[(ni * 16 + l16) * 128 + ko];
#pragma unroll
        for (int mi = 0; mi < 2; ++mi)
#pragma unroll
            for (int ni = 0; ni < 8; ++ni)
                acc[mi][ni] = MFMA16(af[mi], bfr[ni], acc[mi][ni]);
    }
    float biasr[8];
#pragma unroll
    for (int ni = 0; ni < 8; ++ni) biasr[ni] = bias[col0 + ni * 16 + l16];
#pragma unroll
    for (int mi = 0; mi < 2; ++mi)
#pragma unroll
        for (int reg = 0; reg < 4; ++reg) {
            int r = row0 + w * 32 + mi * 16 + lhi * 4 + reg;  // (S,B) row
            u16* crw; int cbase;
            if (col0 == 0) { crw = Cq + (size_t)r * 128; cbase = 0; }
            else           { crw = Ckv + (size_t)r * 256; cbase = col0 - 128; }
#pragma unroll
            for (int ni = 0; ni < 8; ++ni)
                crw[cbase + ni * 16 + l16] = f2b(acc[mi][ni][reg] + biasr[ni]);
        }
}

// ---- merged attention + out-proj + LN + FF + LN (+ next-layer QKV), one block/s ----
// XCD-aware s mapping keeps per-s producer/consumer chains on one XCD.
// Post-attention h never touches global; next-layer QKV reads this block's new h
// straight from A_s (wave-local rows) and writes qb/kvb for the next dispatch.
__global__ __launch_bounds__(256) void attn_ff_kernel(const u16* __restrict__ qb,
                                                      const u16* __restrict__ kvb,
                                                      const u16* __restrict__ wo,
                                                      const float* __restrict__ outb,
                                                      const u16* __restrict__ w1t,
                                                      const u16* __restrict__ w2t,
                                                      const float* __restrict__ b1,
                                                      const float* __restrict__ b2,
                                                      const int* __restrict__ lengths,
                                                      const float* __restrict__ gamma,
                                                      const float* __restrict__ beta,
                                                      const float* __restrict__ pe,
                                                      u16* __restrict__ h,
                                                      const u16* __restrict__ wqn,
                                                      const float* __restrict__ qbn,
                                                      u16* __restrict__ qbo,
                                                      u16* __restrict__ kvbo) {
    const int d = blockIdx.x;
    const int s = ((d & 7) << 1) + ((d >> 3) & 1) + ((d >> 4) << 4);
    const int tid = threadIdx.x, w = tid >> 6, lane = tid & 63;
    const int l16 = lane & 15, lhi = lane >> 4;
    const int xr = (l16 & 7) << 3;
    const int so = w * 512 + lane * 8;

    __shared__ __align__(16) u16 arena[39424];   // 78,848 B
    __shared__ int len_s[64];
    u16* o_s  = arena;            // [64][136] = 8704
    u16* A_s  = arena + 8704;     // [64][128] (LN output -> FF input/residual -> new h)
    u16* T_s  = arena + 16896;    // [64][64]
    u16* Ps   = arena + 20992;    // 4x[64][72] (attn only)
    u16* W1_s = arena + 20992;    // 8192 u16 = 16 KB (aliases Ps after attention)
    u16* W2_s = arena + 29184;    // 8192 u16 = 16 KB

    if (tid < 64) len_s[tid] = lengths[tid];
    __syncthreads();

    bool mk[4];
#pragma unroll
    for (int jt = 0; jt < 4; ++jt) mk[jt] = (s >= len_s[jt * 16 + l16]);

    // ======== attention (q/kv direct from global; P via Ps; PV direct-gather V) ======
    u16* pw = Ps + w * 4608;
#pragma unroll
    for (int hp = 0; hp < 2; ++hp) {
        const int hh = w * 2 + hp;
        short8 af[4];
#pragma unroll
        for (int it = 0; it < 4; ++it) {
            af[it] = (short8){0, 0, 0, 0, 0, 0, 0, 0};
            if (lhi < 2)
                af[it] = *(const short8*)(qb + ((size_t)(s * 64 + it * 16 + l16)) * 128 + hh * 16 + lhi * 8);
        }
        f32x4 sf[4][4];
#pragma unroll
        for (int jt = 0; jt < 4; ++jt) {
            short8 bf = (short8){0, 0, 0, 0, 0, 0, 0, 0};
            if (lhi < 2)
                bf = *(const short8*)(kvb + ((size_t)(s * 64 + jt * 16 + l16)) * 256 + hh * 16 + lhi * 8);
#pragma unroll
            for (int it = 0; it < 4; ++it) {
                f32x4 z = {0.f, 0.f, 0.f, 0.f};
                sf[it][jt] = MFMA16(af[it], bf, z);
            }
        }
        float inv[4][4];
#pragma unroll
        for (int it = 0; it < 4; ++it) {
#pragma unroll
            for (int reg = 0; reg < 4; ++reg) {
                float vv[4], mx = -1e30f;
#pragma unroll
                for (int jt = 0; jt < 4; ++jt) {
                    float xv = mk[jt] ? -1e30f : sf[it][jt][reg] * 0.25f;
                    vv[jt] = xv; mx = fmaxf(mx, xv);
                }
                mx = fmaxf(mx, __shfl_xor(mx, 1)); mx = fmaxf(mx, __shfl_xor(mx, 2));
                mx = fmaxf(mx, __shfl_xor(mx, 4)); mx = fmaxf(mx, __shfl_xor(mx, 8));
                float e4[4], sum = 0.f;
#pragma unroll
                for (int jt = 0; jt < 4; ++jt) {
                    float e = mk[jt] ? 0.f : __expf(vv[jt] - mx);
                    e4[jt] = e; sum += e;
                }
                sum += __shfl_xor(sum, 1); sum += __shfl_xor(sum, 2);
                sum += __shfl_xor(sum, 4); sum += __shfl_xor(sum, 8);
                inv[it][reg] = 1.0f / sum;
                int prow = it * 16 + lhi * 4 + reg;
#pragma unroll
                for (int jt = 0; jt < 4; ++jt)
                    pw[prow * 72 + jt * 16 + l16] = f2b(e4[jt]);
            }
        }
        f32x4 ao[4];
#pragma unroll
        for (int it = 0; it < 4; ++it) ao[it] = (f32x4){0.f, 0.f, 0.f, 0.f};
        short8 vb[2];
#pragma unroll
        for (int ksv = 0; ksv < 2; ++ksv)
#pragma unroll
            for (int e = 0; e < 8; ++e)
                vb[ksv][e] = (short)kvb[((size_t)(s * 64 + ksv * 32 + lhi * 8 + e)) * 256
                                        + 128 + hh * 16 + l16];
#pragma unroll
        for (int it = 0; it < 4; ++it)
#pragma unroll
            for (int ksv = 0; ksv < 2; ++ksv) {
                short8 pa = *(const short8*)&pw[(it * 16 + l16) * 72 + ksv * 32 + lhi * 8];
                ao[it] = MFMA16(pa, vb[ksv], ao[it]);
            }
#pragma unroll
        for (int it = 0; it < 4; ++it)
#pragma unroll
            for (int reg = 0; reg < 4; ++reg)
                o_s[(it * 16 + lhi * 4 + reg) * 136 + hh * 16 + l16] = f2b(ao[it][reg] * inv[it][reg]);
    }
    __syncthreads();   // o_s visible; Ps dead -> W1_s/W2_s usable

    // issue FF W1[0]/W2[0] (fly during out-proj)
#pragma unroll
    for (int i = 0; i < 4; ++i) {
        int slot = i * 2048 + so;
        GLOAD_LDS16(w1t + (size_t)(slot >> 7) * 128 + ((slot & 127) ^ (((slot >> 7) & 7) << 3)),
                    &W1_s[slot]);
        GLOAD_LDS16(w2t + (size_t)(slot >> 6) * 512 + ((slot & 63) ^ (((slot >> 6) & 7) << 3)),
                    &W2_s[slot]);
    }

    // ======== out-proj (wo direct-L2) + bias + residual(h global) + LN -> A_s ========
    {
        f32x4 acc[8];
#pragma unroll
        for (int ni = 0; ni < 8; ++ni) acc[ni] = (f32x4){0.f, 0.f, 0.f, 0.f};
#pragma unroll
        for (int ks = 0; ks < 4; ++ks) {
            short8 af = *(const short8*)&o_s[(w * 16 + l16) * 136 + ks * 32 + lhi * 8];
#pragma unroll
            for (int ni = 0; ni < 8; ++ni) {
                short8 bf = *(const short8*)(wo + (size_t)(ni * 16 + l16) * 128 + ((ks * 32 + lhi * 8) ^ xr));
                acc[ni] = MFMA16(af, bf, acc[ni]);
            }
        }
        float biasr[8], gr[8], br[8];
#pragma unroll
        for (int ni = 0; ni < 8; ++ni) {
            int c = ni * 16 + l16;
            biasr[ni] = outb[c]; gr[ni] = gamma[c]; br[ni] = beta[c];
        }
#pragma unroll
        for (int reg = 0; reg < 4; ++reg) {
            int row = w * 16 + lhi * 4 + reg;
            int xo = (row & 7) << 3;
            size_t rbase = ((size_t)(s * 64 + row)) * 128;
            float v[8], sm = 0.f, s2 = 0.f;
#pragma unroll
            for (int ni = 0; ni < 8; ++ni) {
                float x = acc[ni][reg] + biasr[ni] + b2f(h[rbase + ((ni * 16 + l16) ^ xo)]);
                v[ni] = x; sm += x; s2 += x * x;
            }
            sm += __shfl_xor(sm, 1); sm += __shfl_xor(sm, 2);
            sm += __shfl_xor(sm, 4); sm += __shfl_xor(sm, 8);
            s2 += __shfl_xor(s2, 1); s2 += __shfl_xor(s2, 2);
            s2 += __shfl_xor(s2, 4); s2 += __shfl_xor(s2, 8);
            float mean = sm * (1.0f / 128.0f);
            float var = s2 * (1.0f / 128.0f) - mean * mean;
            float rstd = rsqrtf(fmaxf(var, 0.0f) + 1e-5f);
#pragma unroll
            for (int ni = 0; ni < 8; ++ni)
                A_s[row * 128 + ((ni * 16 + l16) ^ xo)] =
                    f2b((v[ni] - mean) * rstd * gr[ni] + br[ni]);   // wave-local rows
        }
    }
    __syncthreads();   // drains W1[0]/W2[0]; o_s dead

    // ======== FF: nc=8 x 64-col chunks, interleaved dbuf staging ======
    f32x4 acc2[8];
#pragma unroll
    for (int ni = 0; ni < 8; ++ni) acc2[ni] = (f32x4){0.f, 0.f, 0.f, 0.f};
    for (int nc = 0; nc < 8; ++nc) {
        f32x4 acc1[4];
#pragma unroll
        for (int ni = 0; ni < 4; ++ni) acc1[ni] = (f32x4){0.f, 0.f, 0.f, 0.f};
#pragma unroll
        for (int ks = 0; ks < 4; ++ks) {
            const int ko = (ks * 32 + lhi * 8) ^ xr;
            short8 af = *(const short8*)&A_s[(w * 16 + l16) * 128 + ko];
#pragma unroll
            for (int ni = 0; ni < 4; ++ni) {
                short8 bf = *(const short8*)&W1_s[(ni * 16 + l16) * 128 + ko];
                acc1[ni] = MFMA16(af, bf, acc1[ni]);
            }
        }
        float bb[4];
#pragma unroll
        for (int ni = 0; ni < 4; ++ni) bb[ni] = b1[nc * 64 + ni * 16 + l16];
#pragma unroll
        for (int reg = 0; reg < 4; ++reg) {
            int xt = ((lhi * 4 + reg) & 7) << 3;
#pragma unroll
            for (int ni = 0; ni < 4; ++ni)
                T_s[(w * 16 + lhi * 4 + reg) * 64 + ((ni * 16 + l16) ^ xt)] =
                    f2b(fmaxf(acc1[ni][reg] + bb[ni], 0.0f));
        }
        __syncthreads();   // (a) FF1 W1_s reads + T writes done; drains W2[nc]
        if (nc < 7) {
#pragma unroll
            for (int i = 0; i < 4; ++i) {
                int slot = i * 2048 + so;
                GLOAD_LDS16(w1t + (size_t)((nc + 1) * 64 + (slot >> 7)) * 128
                                + ((slot & 127) ^ (((slot >> 7) & 7) << 3)),
                            &W1_s[slot]);
            }
        }
#pragma unroll
        for (int ks = 0; ks < 2; ++ks) {
            const int ko = (ks * 32 + lhi * 8) ^ xr;
            short8 pa = *(const short8*)&T_s[(w * 16 + l16) * 64 + ko];
#pragma unroll
            for (int ni = 0; ni < 8; ++ni) {
                short8 bf = *(const short8*)&W2_s[(ni * 16 + l16) * 64 + ko];
                acc2[ni] = MFMA16(pa, bf, acc2[ni]);
            }
        }
        __syncthreads();   // (b) FF2 W2_s/T reads done; drains W1[nc+1]
        if (nc < 7) {
#pragma unroll
            for (int i = 0; i < 4; ++i) {
                int slot = i * 2048 + so;
                GLOAD_LDS16(w2t + (size_t)(slot >> 6) * 512 + (nc + 1) * 64
                                + ((slot & 63) ^ (((slot >> 6) & 7) << 3)),
                            &W2_s[slot]);
            }
        }
    }
    // if merging next-layer QKV: issue wq chunk0 now (flies during LN epilogue)
    if (wqn) {
#pragma unroll
        for (int i = 0; i < 4; ++i) {
            int slot = i * 2048 + so;
            GLOAD_LDS16(wqn + slot, &W1_s[slot]);
        }
    }
    // ======== FF epilogue: + b2 + residual(A_s) + LN (+pe); write h global (+A_s) ====
    {
        float b2r[8], gr[8], br[8];
#pragma unroll
        for (int ni = 0; ni < 8; ++ni) {
            int c = ni * 16 + l16;
            b2r[ni] = b2[c]; gr[ni] = gamma[c]; br[ni] = beta[c];
        }
#pragma unroll
        for (int reg = 0; reg < 4; ++reg) {
            int lrow = w * 16 + lhi * 4 + reg;
            int xo = (lrow & 7) << 3;
            float v[8], sm = 0.f, s2 = 0.f;
#pragma unroll
            for (int ni = 0; ni < 8; ++ni) {
                float x = acc2[ni][reg] + b2r[ni] + b2f(A_s[lrow * 128 + ((ni * 16 + l16) ^ xo)]);
                v[ni] = x; sm += x; s2 += x * x;
            }
            sm += __shfl_xor(sm, 1); sm += __shfl_xor(sm, 2);
            sm += __shfl_xor(sm, 4); sm += __shfl_xor(sm, 8);
            s2 += __shfl_xor(s2, 1); s2 += __shfl_xor(s2, 2);
            s2 += __shfl_xor(s2, 4); s2 += __shfl_xor(s2, 8);
            float mean = sm * (1.0f / 128.0f);
            float var = s2 * (1.0f / 128.0f) - mean * mean;
            float rstd = rsqrtf(fmaxf(var, 0.0f) + 1e-5f);
            u16* crw = h + ((size_t)(s * 64 + lrow)) * 128;
#pragma unroll
            for (int ni = 0; ni < 8; ++ni) {
                int c = ni * 16 + l16;
                float val = (v[ni] - mean) * rstd * gr[ni] + br[ni];
                if (pe) val += pe[(size_t)s * 128 + c];
                u16 hv = f2b(val);
                crw[c ^ xo] = hv;
                if (wqn) A_s[lrow * 128 + (c ^ xo)] = hv;   // wave-local rows
            }
        }
    }
    if (!wqn) return;

    __syncthreads();   // drains wq chunk0; A_s (new h) visible
    // ======== next-layer QKV: 6 chunks of 64 N-rows (16 KB), dbuf W1_s/W2_s ========
    for (int c = 0; c < 6; ++c) {
        u16* Wcur = (c & 1) ? W2_s : W1_s;
        u16* Wnxt = (c & 1) ? W1_s : W2_s;
        if (c < 5) {
#pragma unroll
            for (int i = 0; i < 4; ++i) {
                int slot = i * 2048 + so;
                GLOAD_LDS16(wqn + (c + 1) * 8192 + slot, &Wnxt[slot]);
            }
        }
        f32x4 acc[4];
#pragma unroll
        for (int ni = 0; ni < 4; ++ni) acc[ni] = (f32x4){0.f, 0.f, 0.f, 0.f};
#pragma unroll
        for (int ks = 0; ks < 4; ++ks) {
            const int ko = (ks * 32 + lhi * 8) ^ xr;
            short8 af = *(const short8*)&A_s[(w * 16 + l16) * 128 + ko];
#pragma unroll
            for (int ni = 0; ni < 4; ++ni) {
                short8 bf = *(const short8*)&Wcur[(ni * 16 + l16) * 128 + ko];
                acc[ni] = MFMA16(af, bf, acc[ni]);
            }
        }
        float bb[4];
#pragma unroll
        for (int ni = 0; ni < 4; ++ni) bb[ni] = qbn[c * 64 + ni * 16 + l16];
#pragma unroll
        for (int reg = 0; reg < 4; ++reg) {
            int row = w * 16 + lhi * 4 + reg;
#pragma unroll
            for (int ni = 0; ni < 4; ++ni) {
                int col = c * 64 + ni * 16 + l16;
                u16 v = f2b(acc[ni][reg] + bb[ni]);
                if (c < 2) qbo[((size_t)(s * 64 + row)) * 128 + col] = v;
                else       kvbo[((size_t)(s * 64 + row)) * 256 + col - 128] = v;
            }
        }
        __syncthreads();   // all reads of Wcur done; drains Wnxt loads
    }
}

// ---------------- masked mean pool + classifier head, one block per b ----------------
__global__ __launch_bounds__(256) void poolhead_kernel(const u16* __restrict__ h,
                                                       const int* __restrict__ lengths,
                                                       const float* __restrict__ fc1w,
                                                       const float* __restrict__ fc1b,
                                                       const float* __restrict__ fc2w,
                                                       const float* __restrict__ fc2b,
                                                       float* __restrict__ out) {
    int b = blockIdx.x, tid = threadIdx.x;
    int e = tid & 127, half = tid >> 7;
    int len = lengths[b];
    int ep = e ^ ((b & 7) << 3);   // h rows (t*64+b): row&7 == b&7
    float s = 0.0f;
    for (int t = half; t < len; t += 2) s += b2f(h[((size_t)(t * 64 + b)) * 128 + ep]);
    __shared__ float red[256];
    __shared__ float mp[128];
    __shared__ float z[32];
    red[tid] = s;
    __syncthreads();
    if (tid < 128) mp[tid] = (red[tid] + red[tid + 128]) / (float)len;
    __syncthreads();
    if (tid < 32) {
        float a = fc1b[tid];
        for (int k = 0; k < 128; ++k) a = fmaf(mp[k], fc1w[k * 32 + tid], a);
        z[tid] = fmaxf(a, 0.0f);
    }
    __syncthreads();
    if (tid == 0) {
        float a = fc2b[0];
#pragma unroll
        for (int t = 0; t < 32; ++t) a = fmaf(z[t], fc2w[t], a);
        out[b] = 1.0f / (1.0f + expf(-a));
    }
}

extern "C" void kernel_launch(void* const* d_in, const int* in_sizes, int n_in,
                              void* d_out, int out_size, void* d_ws, size_t ws_size,
                              hipStream_t stream) {
    (void)in_sizes; (void)n_in; (void)out_size; (void)ws_size;
    const float* x        = (const float*)d_in[0];
    const unsigned char* mask = (const unsigned char*)d_in[1];
    const float* embed_w  = (const float*)d_in[2];
    const float* embed_b  = (const float*)d_in[3];
    const float* qkv_w    = (const float*)d_in[4];
    const float* qkv_b    = (const float*)d_in[5];
    const float* out_w    = (const float*)d_in[6];
    const float* out_b    = (const float*)d_in[7];
    const float* ln_g     = (const float*)d_in[8];
    const float* ln_b     = (const float*)d_in[9];
    const float* ff1_w    = (const float*)d_in[10];
    const float* ff1_b    = (const float*)d_in[11];
    const float* ff2_w    = (const float*)d_in[12];
    const float* ff2_b    = (const float*)d_in[13];
    const float* fc1_w    = (const float*)d_in[14];
    const float* fc1_b    = (const float*)d_in[15];
    const float* fc2_w    = (const float*)d_in[16];
    const float* fc2_b    = (const float*)d_in[17];

    char* wsb = (char*)d_ws;
    int*   lengths = (int*)wsb;                  // 512 B
    float* pe      = (float*)(wsb + 512);        // 256 KiB -> 262656
    u16* wt_embed  = (u16*)(wsb + 262656);       // 256 KiB -> 524800
    u16* wt_qkv    = (u16*)(wsb + 524800);       // 384 KiB -> 918016
    u16* wt_out    = (u16*)(wsb + 918016);       // 128 KiB -> 1049088
    u16* wt_ff1    = (u16*)(wsb + 1049088);      // 512 KiB -> 1573376
    u16* wt_ff2    = (u16*)(wsb + 1573376);      // 512 KiB -> 2097664
    u16* hbuf      = (u16*)(wsb + 2097664);      // 8 MiB  -> 10486272  (S,B, swizzled)
    u16* qb        = (u16*)(wsb + 10486272);     // 8 MiB  -> 18874880
    u16* kvb       = (u16*)(wsb + 18874880);     // 16 MiB -> 35652096

    prep_kernel<<<257, 256, 0, stream>>>(mask, lengths, pe,
                                         embed_w, qkv_w, out_w, ff1_w, ff2_w,
                                         wt_embed, wt_qkv, wt_out, wt_ff1, wt_ff2);

    embed_gemm<<<512, 256, 0, stream>>>(x, wt_embed, embed_b, pe, hbuf);

    // layer-0 QKV standalone; layers 1-3 get QKV from the previous attn_ff tail
    qkv_gemm<<<dim3(256, 3), 256, 0, stream>>>(hbuf, wt_qkv, qkv_b, qb, kvb);

    for (int l = 0; l < NLl; ++l) {
        bool mq = (l < 3);
        attn_ff_kernel<<<512, 256, 0, stream>>>(
            qb, kvb, wt_out + (size_t)l * 16384, out_b + l * 128,
            wt_ff1 + (size_t)l * 65536, wt_ff2 + (size_t)l * 65536,
            ff1_b + l * 512, ff2_b + l * 128,
            lengths, ln_g + l * 128, ln_b + l * 128,
            (l < 3) ? pe : nullptr, hbuf,
            mq ? wt_qkv + (size_t)(l + 1) * 49152 : nullptr,
            mq ? qkv_b + (l + 1) * 384 : nullptr,
            qb, kvb);
    }

    poolhead_kernel<<<64, 256, 0, stream>>>(hbuf, lengths, fc1_w, fc1_b, fc2_w, fc2_b,
                                            (float*)d_out);
}

// Round 15
// 375.292 us; speedup vs baseline: 1.2170x; 1.2170x over previous
//
#include <hip/hip_runtime.h>

#define Bb 64
#define Ss 512
#define INn 1024
#define Ee 128
#define Hh 8
#define Dd 16
#define NLl 4

typedef unsigned short u16;
typedef __attribute__((ext_vector_type(8))) short short8;
typedef __attribute__((ext_vector_type(4))) float f32x4;

__device__ __forceinline__ float b2f(unsigned u) { return __uint_as_float(u << 16); }
__device__ __forceinline__ u16 f2b(float f) {
    unsigned u = __float_as_uint(f);
    unsigned r = u + 0x7FFFu + ((u >> 16) & 1u);
    return (u16)(r >> 16);
}
__device__ __forceinline__ uint2 pk4(float4 f) {
    uint2 r;
    r.x = (unsigned)f2b(f.x) | ((unsigned)f2b(f.y) << 16);
    r.y = (unsigned)f2b(f.z) | ((unsigned)f2b(f.w) << 16);
    return r;
}

#define GLOAD_LDS16(g, l) __builtin_amdgcn_global_load_lds( \
    (const __attribute__((address_space(1))) void*)(g),     \
    (__attribute__((address_space(3))) void*)(l), 16, 0, 0)

#define MFMA16(a, b, c) __builtin_amdgcn_mfma_f32_16x16x32_bf16((a), (b), (c), 0, 0, 0)

// ---------------- prep: lengths (block 0) + pe (1-32) + weight transpose (33-256) ----
// Weights stored TRANSPOSED (N,K), XOR-swizzled: (n,k) lives at k ^ ((n&7)<<3).
__global__ __launch_bounds__(256) void prep_kernel(const unsigned char* __restrict__ m,
                                                   int* __restrict__ lengths,
                                                   float* __restrict__ pe,
                                                   const float* __restrict__ ew,
                                                   const float* __restrict__ qw,
                                                   const float* __restrict__ ow,
                                                   const float* __restrict__ f1w,
                                                   const float* __restrict__ f2w,
                                                   u16* __restrict__ we, u16* __restrict__ wq,
                                                   u16* __restrict__ wo, u16* __restrict__ wf1,
                                                   u16* __restrict__ wf2) {
    const int bid = blockIdx.x, tid = threadIdx.x;
    if (bid == 0) {
        __shared__ int lf[3];
        __shared__ int part[256];
        if (tid < 3) lf[tid] = 0;
        __syncthreads();
        int l0 = 0, l1 = 0, l23 = 0;
        for (int i = tid * 128; i < tid * 128 + 128; ++i) {  // first 32768 bytes: safe
            if (m[i]) { int md = i & 3; if (md == 0) l0 = 1; else if (md == 1) l1 = 1; else l23 = 1; }
        }
        if (l0) atomicOr(&lf[0], 1);
        if (l1) atomicOr(&lf[1], 1);
        if (l23) atomicOr(&lf[2], 1);
        __syncthreads();
        int enc = lf[1] ? 1 : (lf[2] ? 2 : 0);  // 1=uint8, 2=float32, 0=int32
        int b = tid >> 2, q = tid & 3, cnt = 0;
        for (int s = q * 128; s < q * 128 + 128; ++s) {
            int idx = b * Ss + s;
            int mm;
            if (enc == 1)      mm = (m[idx] != 0);
            else if (enc == 2) mm = (((const float*)(const void*)m)[idx] != 0.0f);
            else               mm = (((const int*)(const void*)m)[idx] != 0);
            cnt += (mm == 0);  // monotone mask: zero count == length
        }
        part[tid] = cnt;
        __syncthreads();
        if (tid < 64)
            lengths[tid] = part[tid * 4] + part[tid * 4 + 1] + part[tid * 4 + 2] + part[tid * 4 + 3];
        return;
    }
    if (bid <= 32) {
        for (int i = tid; i < 2048; i += 256) {
            int idx = (bid - 1) * 2048 + i;
            int s = idx >> 7, e = idx & 127;
            float expo = (float)(2 * (e >> 1)) * (1.0f / 128.0f);
            float freq = powf(10000.0f, -expo);
            float angle = (float)s * freq;
            pe[idx] = (e & 1) ? cosf(angle) : sinf(angle);
        }
        return;
    }
    int tb = bid - 33;
    const float* src; u16* dst; int K, N, tile;
    if (tb < 32)       { src = ew;  dst = we;  K = 1024; N = 128; tile = tb; }
    else if (tb < 80)  { int b = tb - 32;  int mat = b >> 2; src = qw  + (size_t)mat * 16384; dst = wq  + (size_t)mat * 16384; K = 128; N = 128; tile = b & 3; }
    else if (tb < 96)  { int b = tb - 80;  int mat = b >> 2; src = ow  + (size_t)mat * 16384; dst = wo  + (size_t)mat * 16384; K = 128; N = 128; tile = b & 3; }
    else if (tb < 160) { int b = tb - 96;  int mat = b >> 4; src = f1w + (size_t)mat * 65536; dst = wf1 + (size_t)mat * 65536; K = 128; N = 512; tile = b & 15; }
    else               { int b = tb - 160; int mat = b >> 4; src = f2w + (size_t)mat * 65536; dst = wf2 + (size_t)mat * 65536; K = 512; N = 128; tile = b & 15; }
    int ktiles = K >> 6;
    int k0 = (tile % ktiles) * 64, n0 = (tile / ktiles) * 64;
    __shared__ __align__(16) u16 t_s[64 * 68];
    int r = tid >> 2, cq = (tid & 3) * 16;
    const float* sp = src + (size_t)(k0 + r) * N + n0 + cq;
#pragma unroll
    for (int i = 0; i < 4; ++i) {
        float4 f = *(const float4*)(sp + 4 * i);
        *(uint2*)&t_s[r * 68 + cq + 4 * i] = pk4(f);
    }
    __syncthreads();
    u16 tmp[16];
#pragma unroll
    for (int kk = 0; kk < 16; ++kk) tmp[kk] = t_s[(cq + kk) * 68 + r];
    int rowg = n0 + r;
    int x = (rowg & 7) << 3;
    u16* base = dst + (size_t)rowg * K;
    *(uint4*)(base + ((k0 + cq) ^ x))     = ((uint4*)tmp)[0];
    *(uint4*)(base + ((k0 + cq + 8) ^ x)) = ((uint4*)tmp)[1];
}

// ------- embed GEMM: h(S,B rows, swizzled) = x(f32) @ wt_embed^T + bias + pe -------
__global__ __launch_bounds__(256) void embed_gemm(const float* __restrict__ X,
                                                  const u16* __restrict__ Wt,
                                                  const float* __restrict__ bias,
                                                  const float* __restrict__ pe,
                                                  u16* __restrict__ C) {
    __shared__ __align__(16) u16 Af[64 * 68];
    __shared__ __align__(16) u16 Bs[2][128 * 64];
    const int tid = threadIdx.x;
    const int w = tid >> 6, lane = tid & 63, l16 = lane & 15, lhi = lane >> 4;
    const int row0 = blockIdx.x * 64;
    const int xr = (l16 & 7) << 3;
    f32x4 acc[8];
#pragma unroll
    for (int ni = 0; ni < 8; ++ni) acc[ni] = (f32x4){0.f, 0.f, 0.f, 0.f};

    const int ar = tid >> 2, ak = (tid & 3) * 16;
    const int crow = tid >> 3, cc8 = (tid & 7) * 8;
    const int wave_lds = w * 512;
    const u16* Bbase = Wt + cc8;
    const float* Arow = X + (size_t)(row0 + ar) * 1024 + ak;

#pragma unroll
    for (int i = 0; i < 4; ++i)
        GLOAD_LDS16(Bbase + (size_t)(i * 32 + crow) * 1024, &Bs[0][i * 2048 + wave_lds]);

    for (int it = 0; it < 16; ++it) {
        const int k0 = it * 64;
        __syncthreads();
#pragma unroll
        for (int i = 0; i < 4; ++i) {
            float4 f = *(const float4*)(Arow + k0 + 4 * i);
            *(uint2*)&Af[ar * 68 + ak + 4 * i] = pk4(f);
        }
        __syncthreads();
        if (it < 15) {
#pragma unroll
            for (int i = 0; i < 4; ++i)
                GLOAD_LDS16(Bbase + (size_t)(i * 32 + crow) * 1024 + k0 + 64,
                            &Bs[(it + 1) & 1][i * 2048 + wave_lds]);
        }
#pragma unroll
        for (int ks = 0; ks < 2; ++ks) {
            short8 af;
            ((uint2*)&af)[0] = *(const uint2*)&Af[(w * 16 + l16) * 68 + ks * 32 + lhi * 8];
            ((uint2*)&af)[1] = *(const uint2*)&Af[(w * 16 + l16) * 68 + ks * 32 + lhi * 8 + 4];
#pragma unroll
            for (int ni = 0; ni < 8; ++ni) {
                short8 bfr = *(const short8*)&Bs[it & 1][(ni * 16 + l16) * 64 + ((ks * 32 + lhi * 8) ^ xr)];
                acc[ni] = MFMA16(af, bfr, acc[ni]);
            }
        }
    }
    float biasr[8];
#pragma unroll
    for (int ni = 0; ni < 8; ++ni) biasr[ni] = bias[ni * 16 + l16];
#pragma unroll
    for (int reg = 0; reg < 4; ++reg) {
        int r = row0 + w * 16 + lhi * 4 + reg;      // b-major row b*512+s
        int s = r & 511;
        int bidx = r >> 9;
        int orow = s * 64 + bidx;                   // (S,B) row
        int xo = (bidx & 7) << 3;
        const float* per = pe + (size_t)s * 128;
        u16* crw = C + (size_t)orow * 128;
#pragma unroll
        for (int ni = 0; ni < 8; ++ni) {
            int c = ni * 16 + l16;
            crw[c ^ xo] = f2b(acc[ni][reg] + biasr[ni] + per[c]);
        }
    }
}

// ------- QKV GEMM: K=128 single-shot; A (swizzled h) and W staged via gload_lds ----
__global__ __launch_bounds__(256) void qkv_gemm(const u16* __restrict__ A,
                                                const u16* __restrict__ Wt,
                                                const float* __restrict__ bias,
                                                u16* __restrict__ Cq,
                                                u16* __restrict__ Ckv) {
    __shared__ __align__(16) u16 As[128 * 128];
    __shared__ __align__(16) u16 Bs[128 * 128];
    const int tid = threadIdx.x, w = tid >> 6, lane = tid & 63;
    const int l16 = lane & 15, lhi = lane >> 4;
    const int row0 = blockIdx.x * 128, col0 = blockIdx.y * 128;
    const int so = w * 512 + lane * 8;
    const int xr = (l16 & 7) << 3;
#pragma unroll
    for (int i = 0; i < 8; ++i) {
        GLOAD_LDS16(A + (size_t)row0 * 128 + i * 2048 + so, &As[i * 2048 + w * 512]);
        GLOAD_LDS16(Wt + (size_t)col0 * 128 + i * 2048 + so, &Bs[i * 2048 + w * 512]);
    }
    __syncthreads();
    f32x4 acc[2][8];
#pragma unroll
    for (int mi = 0; mi < 2; ++mi)
#pragma unroll
        for (int ni = 0; ni < 8; ++ni) acc[mi][ni] = (f32x4){0.f, 0.f, 0.f, 0.f};
#pragma unroll
    for (int ks = 0; ks < 4; ++ks) {
        const int ko = (ks * 32 + lhi * 8) ^ xr;
        short8 af[2], bfr[8];
#pragma unroll
        for (int mi = 0; mi < 2; ++mi)
            af[mi] = *(const short8*)&As[(w * 32 + mi * 16 + l16) * 128 + ko];
#pragma unroll
        for (int ni = 0; ni < 8; ++ni)
            bfr[ni] = *(const short8*)&Bs[(ni * 16 + l16) * 128 + ko];
#pragma unroll
        for (int mi = 0; mi < 2; ++mi)
#pragma unroll
            for (int ni = 0; ni < 8; ++ni)
                acc[mi][ni] = MFMA16(af[mi], bfr[ni], acc[mi][ni]);
    }
    float biasr[8];
#pragma unroll
    for (int ni = 0; ni < 8; ++ni) biasr[ni] = bias[col0 + ni * 16 + l16];
#pragma unroll
    for (int mi = 0; mi < 2; ++mi)
#pragma unroll
        for (int reg = 0; reg < 4; ++reg) {
            int r = row0 + w * 32 + mi * 16 + lhi * 4 + reg;  // (S,B) row
            u16* crw; int cbase;
            if (col0 == 0) { crw = Cq + (size_t)r * 128; cbase = 0; }
            else           { crw = Ckv + (size_t)r * 256; cbase = col0 - 128; }
#pragma unroll
            for (int ni = 0; ni < 8; ++ni)
                crw[cbase + ni * 16 + l16] = f2b(acc[mi][ni][reg] + biasr[ni]);
        }
}

// ---- merged attention + out-proj + LN + FF + LN, one block per s; 79.1KB LDS ----
// XCD-aware s mapping: s = 2(d&7) + ((d>>3)&1) + 16(d>>4)  (bijective; matches
// qkv producer block x=s>>1 on XCD x%8 and next-layer qkv consumer).
// Post-attention h is never written to global (dead); LN result goes to A_s.
__global__ __launch_bounds__(256) void attn_ff_kernel(const u16* __restrict__ qb,
                                                      const u16* __restrict__ kvb,
                                                      const u16* __restrict__ wo,
                                                      const float* __restrict__ outb,
                                                      const u16* __restrict__ w1t,
                                                      const u16* __restrict__ w2t,
                                                      const float* __restrict__ b1,
                                                      const float* __restrict__ b2,
                                                      const int* __restrict__ lengths,
                                                      const float* __restrict__ gamma,
                                                      const float* __restrict__ beta,
                                                      const float* __restrict__ pe,
                                                      u16* __restrict__ h) {
    const int d = blockIdx.x;
    const int s = ((d & 7) << 1) + ((d >> 3) & 1) + ((d >> 4) << 4);
    const int tid = threadIdx.x, w = tid >> 6, lane = tid & 63;
    const int l16 = lane & 15, lhi = lane >> 4;
    const int xr = (l16 & 7) << 3;
    const int so = w * 512 + lane * 8;

    __shared__ __align__(16) u16 arena[39424];   // 78,848 B
    __shared__ int len_s[64];
    u16* o_s  = arena;            // [64][136] = 8704
    u16* A_s  = arena + 8704;     // [64][128] = 8192 (LN output -> FF input/residual)
    u16* T_s  = arena + 16896;    // [64][64]  = 4096
    u16* Ps   = arena + 20992;    // 4x[64][72] = 18432 (attn only)
    u16* W1_s = arena + 20992;    // 8192 (aliases Ps after attention)
    u16* W2_s = arena + 29184;    // 8192

    if (tid < 64) len_s[tid] = lengths[tid];
    __syncthreads();

    bool mk[4];
#pragma unroll
    for (int jt = 0; jt < 4; ++jt) mk[jt] = (s >= len_s[jt * 16 + l16]);

    // ======== attention (q/kv direct from global; P via Ps; PV direct-gather V) ======
    u16* pw = Ps + w * 4608;
#pragma unroll
    for (int hp = 0; hp < 2; ++hp) {
        const int hh = w * 2 + hp;
        short8 af[4];
#pragma unroll
        for (int it = 0; it < 4; ++it) {
            af[it] = (short8){0, 0, 0, 0, 0, 0, 0, 0};
            if (lhi < 2)
                af[it] = *(const short8*)(qb + ((size_t)(s * 64 + it * 16 + l16)) * 128 + hh * 16 + lhi * 8);
        }
        f32x4 sf[4][4];
#pragma unroll
        for (int jt = 0; jt < 4; ++jt) {
            short8 bf = (short8){0, 0, 0, 0, 0, 0, 0, 0};
            if (lhi < 2)
                bf = *(const short8*)(kvb + ((size_t)(s * 64 + jt * 16 + l16)) * 256 + hh * 16 + lhi * 8);
#pragma unroll
            for (int it = 0; it < 4; ++it) {
                f32x4 z = {0.f, 0.f, 0.f, 0.f};
                sf[it][jt] = MFMA16(af[it], bf, z);
            }
        }
        float inv[4][4];
#pragma unroll
        for (int it = 0; it < 4; ++it) {
#pragma unroll
            for (int reg = 0; reg < 4; ++reg) {
                float vv[4], mx = -1e30f;
#pragma unroll
                for (int jt = 0; jt < 4; ++jt) {
                    float xv = mk[jt] ? -1e30f : sf[it][jt][reg] * 0.25f;
                    vv[jt] = xv; mx = fmaxf(mx, xv);
                }
                mx = fmaxf(mx, __shfl_xor(mx, 1)); mx = fmaxf(mx, __shfl_xor(mx, 2));
                mx = fmaxf(mx, __shfl_xor(mx, 4)); mx = fmaxf(mx, __shfl_xor(mx, 8));
                float e4[4], sum = 0.f;
#pragma unroll
                for (int jt = 0; jt < 4; ++jt) {
                    float e = mk[jt] ? 0.f : __expf(vv[jt] - mx);
                    e4[jt] = e; sum += e;
                }
                sum += __shfl_xor(sum, 1); sum += __shfl_xor(sum, 2);
                sum += __shfl_xor(sum, 4); sum += __shfl_xor(sum, 8);
                inv[it][reg] = 1.0f / sum;
                int prow = it * 16 + lhi * 4 + reg;
#pragma unroll
                for (int jt = 0; jt < 4; ++jt)
                    pw[prow * 72 + jt * 16 + l16] = f2b(e4[jt]);
            }
        }
        f32x4 ao[4];
#pragma unroll
        for (int it = 0; it < 4; ++it) ao[it] = (f32x4){0.f, 0.f, 0.f, 0.f};
        short8 vb[2];
#pragma unroll
        for (int ksv = 0; ksv < 2; ++ksv)
#pragma unroll
            for (int e = 0; e < 8; ++e)
                vb[ksv][e] = (short)kvb[((size_t)(s * 64 + ksv * 32 + lhi * 8 + e)) * 256
                                        + 128 + hh * 16 + l16];
#pragma unroll
        for (int it = 0; it < 4; ++it)
#pragma unroll
            for (int ksv = 0; ksv < 2; ++ksv) {
                short8 pa = *(const short8*)&pw[(it * 16 + l16) * 72 + ksv * 32 + lhi * 8];
                ao[it] = MFMA16(pa, vb[ksv], ao[it]);
            }
#pragma unroll
        for (int it = 0; it < 4; ++it)
#pragma unroll
            for (int reg = 0; reg < 4; ++reg)
                o_s[(it * 16 + lhi * 4 + reg) * 136 + hh * 16 + l16] = f2b(ao[it][reg] * inv[it][reg]);
    }
    __syncthreads();   // o_s visible; Ps dead -> W1_s/W2_s usable

    // issue FF W1[0]/W2[0] (fly during out-proj)
#pragma unroll
    for (int i = 0; i < 4; ++i) {
        int slot = i * 2048 + so;
        GLOAD_LDS16(w1t + (size_t)(slot >> 7) * 128 + ((slot & 127) ^ (((slot >> 7) & 7) << 3)),
                    &W1_s[slot]);
        GLOAD_LDS16(w2t + (size_t)(slot >> 6) * 512 + ((slot & 63) ^ (((slot >> 6) & 7) << 3)),
                    &W2_s[slot]);
    }

    // ======== out-proj (wo direct-L2) + bias + residual(h global) + LN -> A_s ========
    {
        f32x4 acc[8];
#pragma unroll
        for (int ni = 0; ni < 8; ++ni) acc[ni] = (f32x4){0.f, 0.f, 0.f, 0.f};
#pragma unroll
        for (int ks = 0; ks < 4; ++ks) {
            short8 af = *(const short8*)&o_s[(w * 16 + l16) * 136 + ks * 32 + lhi * 8];
#pragma unroll
            for (int ni = 0; ni < 8; ++ni) {
                short8 bf = *(const short8*)(wo + (size_t)(ni * 16 + l16) * 128 + ((ks * 32 + lhi * 8) ^ xr));
                acc[ni] = MFMA16(af, bf, acc[ni]);
            }
        }
        float biasr[8], gr[8], br[8];
#pragma unroll
        for (int ni = 0; ni < 8; ++ni) {
            int c = ni * 16 + l16;
            biasr[ni] = outb[c]; gr[ni] = gamma[c]; br[ni] = beta[c];
        }
#pragma unroll
        for (int reg = 0; reg < 4; ++reg) {
            int row = w * 16 + lhi * 4 + reg;
            int xo = (row & 7) << 3;
            size_t rbase = ((size_t)(s * 64 + row)) * 128;
            float v[8], sm = 0.f, s2 = 0.f;
#pragma unroll
            for (int ni = 0; ni < 8; ++ni) {
                float x = acc[ni][reg] + biasr[ni] + b2f(h[rbase + ((ni * 16 + l16) ^ xo)]);
                v[ni] = x; sm += x; s2 += x * x;
            }
            sm += __shfl_xor(sm, 1); sm += __shfl_xor(sm, 2);
            sm += __shfl_xor(sm, 4); sm += __shfl_xor(sm, 8);
            s2 += __shfl_xor(s2, 1); s2 += __shfl_xor(s2, 2);
            s2 += __shfl_xor(s2, 4); s2 += __shfl_xor(s2, 8);
            float mean = sm * (1.0f / 128.0f);
            float var = s2 * (1.0f / 128.0f) - mean * mean;
            float rstd = rsqrtf(fmaxf(var, 0.0f) + 1e-5f);
#pragma unroll
            for (int ni = 0; ni < 8; ++ni)
                A_s[row * 128 + ((ni * 16 + l16) ^ xo)] =
                    f2b((v[ni] - mean) * rstd * gr[ni] + br[ni]);   // wave-local rows
        }
    }
    __syncthreads();   // drains W1[0]/W2[0]; o_s dead

    // ======== FF: nc=8 x 64-col chunks, interleaved dbuf staging (r12 pattern) ======
    f32x4 acc2[8];
#pragma unroll
    for (int ni = 0; ni < 8; ++ni) acc2[ni] = (f32x4){0.f, 0.f, 0.f, 0.f};
    for (int nc = 0; nc < 8; ++nc) {
        f32x4 acc1[4];
#pragma unroll
        for (int ni = 0; ni < 4; ++ni) acc1[ni] = (f32x4){0.f, 0.f, 0.f, 0.f};
#pragma unroll
        for (int ks = 0; ks < 4; ++ks) {
            const int ko = (ks * 32 + lhi * 8) ^ xr;
            short8 af = *(const short8*)&A_s[(w * 16 + l16) * 128 + ko];
#pragma unroll
            for (int ni = 0; ni < 4; ++ni) {
                short8 bf = *(const short8*)&W1_s[(ni * 16 + l16) * 128 + ko];
                acc1[ni] = MFMA16(af, bf, acc1[ni]);
            }
        }
        float bb[4];
#pragma unroll
        for (int ni = 0; ni < 4; ++ni) bb[ni] = b1[nc * 64 + ni * 16 + l16];
#pragma unroll
        for (int reg = 0; reg < 4; ++reg) {
            int xt = ((lhi * 4 + reg) & 7) << 3;
#pragma unroll
            for (int ni = 0; ni < 4; ++ni)
                T_s[(w * 16 + lhi * 4 + reg) * 64 + ((ni * 16 + l16) ^ xt)] =
                    f2b(fmaxf(acc1[ni][reg] + bb[ni], 0.0f));
        }
        __syncthreads();   // (a) FF1 W1_s reads + T writes done; drains W2[nc]
        if (nc < 7) {
#pragma unroll
            for (int i = 0; i < 4; ++i) {
                int slot = i * 2048 + so;
                GLOAD_LDS16(w1t + (size_t)((nc + 1) * 64 + (slot >> 7)) * 128
                                + ((slot & 127) ^ (((slot >> 7) & 7) << 3)),
                            &W1_s[slot]);
            }
        }
#pragma unroll
        for (int ks = 0; ks < 2; ++ks) {
            const int ko = (ks * 32 + lhi * 8) ^ xr;
            short8 pa = *(const short8*)&T_s[(w * 16 + l16) * 64 + ko];
#pragma unroll
            for (int ni = 0; ni < 8; ++ni) {
                short8 bf = *(const short8*)&W2_s[(ni * 16 + l16) * 64 + ko];
                acc2[ni] = MFMA16(pa, bf, acc2[ni]);
            }
        }
        __syncthreads();   // (b) FF2 W2_s/T reads done; drains W1[nc+1]
        if (nc < 7) {
#pragma unroll
            for (int i = 0; i < 4; ++i) {
                int slot = i * 2048 + so;
                GLOAD_LDS16(w2t + (size_t)(slot >> 6) * 512 + (nc + 1) * 64
                                + ((slot & 63) ^ (((slot >> 6) & 7) << 3)),
                            &W2_s[slot]);
            }
        }
    }
    // ======== FF epilogue: + b2 + residual(A_s) + LN (+pe); write h global ========
    float b2r[8], gr[8], br[8];
#pragma unroll
    for (int ni = 0; ni < 8; ++ni) {
        int c = ni * 16 + l16;
        b2r[ni] = b2[c]; gr[ni] = gamma[c]; br[ni] = beta[c];
    }
#pragma unroll
    for (int reg = 0; reg < 4; ++reg) {
        int lrow = w * 16 + lhi * 4 + reg;
        int xo = (lrow & 7) << 3;
        float v[8], sm = 0.f, s2 = 0.f;
#pragma unroll
        for (int ni = 0; ni < 8; ++ni) {
            float x = acc2[ni][reg] + b2r[ni] + b2f(A_s[lrow * 128 + ((ni * 16 + l16) ^ xo)]);
            v[ni] = x; sm += x; s2 += x * x;
        }
        sm += __shfl_xor(sm, 1); sm += __shfl_xor(sm, 2);
        sm += __shfl_xor(sm, 4); sm += __shfl_xor(sm, 8);
        s2 += __shfl_xor(s2, 1); s2 += __shfl_xor(s2, 2);
        s2 += __shfl_xor(s2, 4); s2 += __shfl_xor(s2, 8);
        float mean = sm * (1.0f / 128.0f);
        float var = s2 * (1.0f / 128.0f) - mean * mean;
        float rstd = rsqrtf(fmaxf(var, 0.0f) + 1e-5f);
        u16* crw = h + ((size_t)(s * 64 + lrow)) * 128;
#pragma unroll
        for (int ni = 0; ni < 8; ++ni) {
            int c = ni * 16 + l16;
            float val = (v[ni] - mean) * rstd * gr[ni] + br[ni];
            if (pe) val += pe[(size_t)s * 128 + c];
            crw[c ^ xo] = f2b(val);
        }
    }
}

// ---------------- masked mean pool + classifier head, one block per b ----------------
__global__ __launch_bounds__(256) void poolhead_kernel(const u16* __restrict__ h,
                                                       const int* __restrict__ lengths,
                                                       const float* __restrict__ fc1w,
                                                       const float* __restrict__ fc1b,
                                                       const float* __restrict__ fc2w,
                                                       const float* __restrict__ fc2b,
                                                       float* __restrict__ out) {
    int b = blockIdx.x, tid = threadIdx.x;
    int e = tid & 127, half = tid >> 7;
    int len = lengths[b];
    int ep = e ^ ((b & 7) << 3);   // h rows (t*64+b): row&7 == b&7
    float s = 0.0f;
    for (int t = half; t < len; t += 2) s += b2f(h[((size_t)(t * 64 + b)) * 128 + ep]);
    __shared__ float red[256];
    __shared__ float mp[128];
    __shared__ float z[32];
    red[tid] = s;
    __syncthreads();
    if (tid < 128) mp[tid] = (red[tid] + red[tid + 128]) / (float)len;
    __syncthreads();
    if (tid < 32) {
        float a = fc1b[tid];
        for (int k = 0; k < 128; ++k) a = fmaf(mp[k], fc1w[k * 32 + tid], a);
        z[tid] = fmaxf(a, 0.0f);
    }
    __syncthreads();
    if (tid == 0) {
        float a = fc2b[0];
#pragma unroll
        for (int t = 0; t < 32; ++t) a = fmaf(z[t], fc2w[t], a);
        out[b] = 1.0f / (1.0f + expf(-a));
    }
}

extern "C" void kernel_launch(void* const* d_in, const int* in_sizes, int n_in,
                              void* d_out, int out_size, void* d_ws, size_t ws_size,
                              hipStream_t stream) {
    (void)in_sizes; (void)n_in; (void)out_size; (void)ws_size;
    const float* x        = (const float*)d_in[0];
    const unsigned char* mask = (const unsigned char*)d_in[1];
    const float* embed_w  = (const float*)d_in[2];
    const float* embed_b  = (const float*)d_in[3];
    const float* qkv_w    = (const float*)d_in[4];
    const float* qkv_b    = (const float*)d_in[5];
    const float* out_w    = (const float*)d_in[6];
    const float* out_b    = (const float*)d_in[7];
    const float* ln_g     = (const float*)d_in[8];
    const float* ln_b     = (const float*)d_in[9];
    const float* ff1_w    = (const float*)d_in[10];
    const float* ff1_b    = (const float*)d_in[11];
    const float* ff2_w    = (const float*)d_in[12];
    const float* ff2_b    = (const float*)d_in[13];
    const float* fc1_w    = (const float*)d_in[14];
    const float* fc1_b    = (const float*)d_in[15];
    const float* fc2_w    = (const float*)d_in[16];
    const float* fc2_b    = (const float*)d_in[17];

    char* wsb = (char*)d_ws;
    int*   lengths = (int*)wsb;                  // 512 B
    float* pe      = (float*)(wsb + 512);        // 256 KiB -> 262656
    u16* wt_embed  = (u16*)(wsb + 262656);       // 256 KiB -> 524800
    u16* wt_qkv    = (u16*)(wsb + 524800);       // 384 KiB -> 918016
    u16* wt_out    = (u16*)(wsb + 918016);       // 128 KiB -> 1049088
    u16* wt_ff1    = (u16*)(wsb + 1049088);      // 512 KiB -> 1573376
    u16* wt_ff2    = (u16*)(wsb + 1573376);      // 512 KiB -> 2097664
    u16* hbuf      = (u16*)(wsb + 2097664);      // 8 MiB  -> 10486272  (S,B, swizzled)
    u16* qb        = (u16*)(wsb + 10486272);     // 8 MiB  -> 18874880
    u16* kvb       = (u16*)(wsb + 18874880);     // 16 MiB -> 35652096

    prep_kernel<<<257, 256, 0, stream>>>(mask, lengths, pe,
                                         embed_w, qkv_w, out_w, ff1_w, ff2_w,
                                         wt_embed, wt_qkv, wt_out, wt_ff1, wt_ff2);

    embed_gemm<<<512, 256, 0, stream>>>(x, wt_embed, embed_b, pe, hbuf);

    for (int l = 0; l < NLl; ++l) {
        qkv_gemm<<<dim3(256, 3), 256, 0, stream>>>(
            hbuf, wt_qkv + (size_t)l * 49152, qkv_b + l * 384, qb, kvb);
        attn_ff_kernel<<<512, 256, 0, stream>>>(
            qb, kvb, wt_out + (size_t)l * 16384, out_b + l * 128,
            wt_ff1 + (size_t)l * 65536, wt_ff2 + (size_t)l * 65536,
            ff1_b + l * 512, ff2_b + l * 128,
            lengths, ln_g + l * 128, ln_b + l * 128,
            (l < 3) ? pe : nullptr, hbuf);
    }

    poolhead_kernel<<<64, 256, 0, stream>>>(hbuf, lengths, fc1_w, fc1_b, fc2_w, fc2_b,
                                            (float*)d_out);
}